// Round 25
// baseline (135.702 us; speedup 1.0000x reference)
//
#include <hip/hip_runtime.h>
#include <math.h>

// GptOssRouter: T=16384, H=2880, E=128, K=4.
// r25 = r24 with the cvt_pkrtz return-type fix (__fp16 vector, not _Float16).
// SPLIT topology: r5's K1 (fastest GEMM of the session, 43us measured) with
// fp16 (cvt_pkrtz) instead of bf16, + r8's certified-gap K2 (~18us measured).
// K1: 32tok x 64exp per block, grid=1024 (4 blocks/CU), LDS-staged x AND w
//     (fp16), double-buffered, 1 barrier/chunk, reg prefetch. Logits -> out.
// K2: 2 tokens/block: rank-based top-8 from logits; certified-gap TAU=1e-2
//     (>=6 sigma of RTZ-fp16 logit err ~1.5e-3): fast fp32 softmax; ~13%
//     tokens fp64-rescore top-8 (order == float64 numpy reference).

#define T_TOK 16384
#define HDIM  2880
#define EEXP  128
#define KTOP  4

// ---------------- Kernel 1 (r5 structure, fp16) ----------------
#define TM    32            // tokens per block
#define EN    64            // experts per block
#define NT1   256           // 4 waves
#define KC    64            // K-chunk (2880 = 45*64)
#define NCH   (HDIM / KC)   // 45
#define LDROW 144           // fp16 LDS row stride in BYTES (128B payload + 16)
#define ROWS  (TM + EN)     // 96 rows per buffer
#define BUFB  (ROWS * LDROW)// 13824 B per buffer
#define NPF   6             // float4 staged per thread per chunk

typedef __attribute__((ext_vector_type(8))) _Float16 f16x8;
typedef __attribute__((ext_vector_type(4))) float    f32x4;

#define MFMA16(a, b, c) __builtin_amdgcn_mfma_f32_16x16x32_f16((a), (b), (c), 0, 0, 0)

// pack fp16(a), fp16(b) (RTZ) into one u32 via v_cvt_pkrtz_f16_f32
static __device__ __forceinline__ unsigned pack2h(float a, float b) {
    union { __attribute__((ext_vector_type(2))) __fp16 h; unsigned u; } U;
    U.h = __builtin_amdgcn_cvt_pkrtz(a, b);
    return U.u;
}

__global__ __launch_bounds__(NT1, 4) void router_gemm(
    const float* __restrict__ x, const float* __restrict__ w,
    const float* __restrict__ bias, float* __restrict__ out)
{
    __shared__ char smem[2 * BUFB];     // 27648 B
    const int tid = threadIdx.x;
    const int blk = blockIdx.x;
    const int xcd = blk & 7;
    const int j   = blk >> 3;           // 0..127 within XCD
    const int be  = j & 1;              // expert half
    const int p   = xcd * 64 + (j >> 1);// token tile 0..511
    const int tok0 = p * TM;
    const int e0   = be * EN;

    const int lane = tid & 63;
    const int wv   = tid >> 6;
    const int wt   = wv & 1;            // token 16-row group
    const int wn   = wv >> 1;           // expert 32-col group
    const int r    = lane & 15;
    const int g    = lane >> 4;

    // staging map: 96 rows x 16 float4 = 1536 float4, 6 per thread
    const float* sptr[NPF];
    int soff[NPF];
#pragma unroll
    for (int i = 0; i < NPF; ++i) {
        int f = tid + i * NT1;
        int row = f >> 4, c4 = f & 15;
        soff[i] = row * LDROW + c4 * 8;
        sptr[i] = (row < TM) ? (x + (size_t)(tok0 + row) * HDIM + c4 * 4)
                             : (w + (size_t)(e0 + row - TM) * HDIM + c4 * 4);
    }

    f32x4 acc[2];
    const f32x4 zf = {0.f, 0.f, 0.f, 0.f};
    acc[0] = zf; acc[1] = zf;

    float4 pf[NPF];
    // prologue: chunk 0 -> regs -> buf0
#pragma unroll
    for (int i = 0; i < NPF; ++i) pf[i] = *(const float4*)sptr[i];
#pragma unroll
    for (int i = 0; i < NPF; ++i) {
        uint2 c; c.x = pack2h(pf[i].x, pf[i].y); c.y = pack2h(pf[i].z, pf[i].w);
        *(uint2*)(smem + soff[i]) = c;
    }
    __syncthreads();

    for (int c = 0; c < NCH; ++c) {
        char* cb = smem + (c & 1) * BUFB;        // compute buffer
        char* sb = smem + ((c & 1) ^ 1) * BUFB;  // stage buffer
        const bool more = (c + 1 < NCH);
        if (more) {
            int koff = (c + 1) * KC;
#pragma unroll
            for (int i = 0; i < NPF; ++i)
                pf[i] = *(const float4*)(sptr[i] + koff);
        }
#pragma unroll
        for (int ks = 0; ks < KC / 32; ++ks) {
            f16x8 af = *(const f16x8*)(cb + (wt * 16 + r) * LDROW + ks * 64 + g * 16);
#pragma unroll
            for (int n = 0; n < 2; ++n) {
                f16x8 bfr = *(const f16x8*)(cb + (TM + wn * 32 + n * 16 + r) * LDROW + ks * 64 + g * 16);
                acc[n] = MFMA16(af, bfr, acc[n]);
            }
        }
        if (more) {
#pragma unroll
            for (int i = 0; i < NPF; ++i) {
                uint2 cv; cv.x = pack2h(pf[i].x, pf[i].y); cv.y = pack2h(pf[i].z, pf[i].w);
                *(uint2*)(sb + soff[i]) = cv;
            }
        }
        __syncthreads();
    }

    // epilogue: logits(+bias) -> out score rows (scratch for K2)
#pragma unroll
    for (int n = 0; n < 2; ++n) {
        int e = e0 + wn * 32 + n * 16 + r;
        float bv = bias[e];
#pragma unroll
        for (int q = 0; q < 4; ++q) {
            int m = wt * 16 + g * 4 + q;
            out[(size_t)(tok0 + m) * EEXP + e] = acc[n][q] + bv;
        }
    }
}

// ---------------- Kernel 2 (r8 structure, TAU=1e-2) ----------------
#define NT2 256
#define TAU 1e-2f

__global__ __launch_bounds__(NT2) void router_select(
    const float* __restrict__ x, const float* __restrict__ w,
    const float* __restrict__ bias, float* __restrict__ out)
{
    __shared__ float  lrow[2][EEXP];
    __shared__ float  srow[2][EEXP];
    __shared__ float  cvf[2][8];
    __shared__ int    cie[2][8];
    __shared__ double cvd[2][8];
    __shared__ double sv4[2][4];
    __shared__ int    si4[2][4];
    __shared__ int    flg[2];

    const int tid = threadIdx.x;
    const int tg  = tid >> 7;           // token group 0/1
    const int e   = tid & 127;
    const int t   = blockIdx.x * 2 + tg;
    float* orow = out + (size_t)t * EEXP;

    float my = orow[e];                 // coalesced logit load
    lrow[tg][e] = my;
    srow[tg][e] = 0.f;
    __syncthreads();

    // parallel rank among 128 (strict total order, index tie-break)
    int rank = 0;
    const float4* lr4 = (const float4*)lrow[tg];
#pragma unroll 8
    for (int j4 = 0; j4 < EEXP / 4; ++j4) {
        float4 lv = lr4[j4];
        int jb = j4 * 4;
        rank += (lv.x > my) || (lv.x == my && (jb + 0) < e);
        rank += (lv.y > my) || (lv.y == my && (jb + 1) < e);
        rank += (lv.z > my) || (lv.z == my && (jb + 2) < e);
        rank += (lv.w > my) || (lv.w == my && (jb + 3) < e);
    }
    if (rank < 8) { cvf[tg][rank] = my; cie[tg][rank] = e; }
    __syncthreads();

    // certified-gap test on the 4 order-relevant gaps
    if (e == 0) {
        float gmin = 3.4e38f;
#pragma unroll
        for (int k = 0; k < 4; ++k)
            gmin = fminf(gmin, cvf[tg][k] - cvf[tg][k + 1]);
        flg[tg] = (gmin < TAU);
    }
    __syncthreads();
    const bool slow = (flg[tg] != 0);

    if (slow) {                          // fp64 re-accumulation, 16 lanes/cand
        const int c = e >> 4, s = e & 15;
        const int ce = cie[tg][c];
        const float4* xr = (const float4*)(x + (size_t)t * HDIM);
        const float4* wr = (const float4*)(w + (size_t)ce * HDIM);
        double a0 = 0.0, a1 = 0.0, a2 = 0.0, a3 = 0.0;
        for (int i = 0; i < 45; ++i) {  // 45*16 = 720 float4
            int fi = s + i * 16;
            float4 xv = xr[fi];
            float4 wv = wr[fi];
            a0 = fma((double)xv.x, (double)wv.x, a0);
            a1 = fma((double)xv.y, (double)wv.y, a1);
            a2 = fma((double)xv.z, (double)wv.z, a2);
            a3 = fma((double)xv.w, (double)wv.w, a3);
        }
        double acc = (a0 + a2) + (a1 + a3);
#pragma unroll
        for (int off = 8; off > 0; off >>= 1)
            acc += __shfl_xor(acc, off); // closes within each 16-lane group
        if (s == 0) cvd[tg][c] = acc + (double)bias[ce];
    }
    __syncthreads();
    if (slow && e < 8) {                 // fp64 rank among the 8 candidates
        double mv = cvd[tg][e]; int mi = cie[tg][e];
        int rk = 0;
#pragma unroll
        for (int j2 = 0; j2 < 8; ++j2) {
            double oj = cvd[tg][j2];
            rk += (oj > mv) || (oj == mv && cie[tg][j2] < mi);
        }
        if (rk < 4) { sv4[tg][rk] = mv; si4[tg][rk] = mi; }
    }
    __syncthreads();

    if (e < 4) {
        float sc; int id;
        if (slow) {
            double m = sv4[tg][0];
            double s0 = exp(sv4[tg][0] - m), s1 = exp(sv4[tg][1] - m);
            double s2 = exp(sv4[tg][2] - m), s3 = exp(sv4[tg][3] - m);
            double ssum = ((s0 + s1) + (s2 + s3));
            double ek = exp(sv4[tg][e] - m);
            sc = (float)(ek / ssum); id = si4[tg][e];
        } else {
            float m = cvf[tg][0];
            float s0 = expf(cvf[tg][0] - m), s1 = expf(cvf[tg][1] - m);
            float s2 = expf(cvf[tg][2] - m), s3 = expf(cvf[tg][3] - m);
            float ssum = ((s0 + s1) + (s2 + s3));
            sc = expf(cvf[tg][e] - m) / ssum; id = cie[tg][e];
        }
        out[(size_t)T_TOK * EEXP + (size_t)t * KTOP + e] = (float)id;
        srow[tg][id] = sc;
    }
    __syncthreads();

    if (e < 32) ((float4*)orow)[e] = ((float4*)srow[tg])[e];
}

extern "C" void kernel_launch(void* const* d_in, const int* in_sizes, int n_in,
                              void* d_out, int out_size, void* d_ws, size_t ws_size,
                              hipStream_t stream) {
    const float* x    = (const float*)d_in[0];
    const float* w    = (const float*)d_in[1];
    const float* bias = (const float*)d_in[2];
    float* out        = (float*)d_out;

    hipLaunchKernelGGL(router_gemm, dim3((T_TOK / TM) * (EEXP / EN)), dim3(NT1),
                       0, stream, x, w, bias, out);
    hipLaunchKernelGGL(router_select, dim3(T_TOK / 2), dim3(NT2), 0, stream,
                       x, w, bias, out);
}

// Round 26
// 79.233 us; speedup vs baseline: 1.7127x; 1.7127x over previous
//
#include <hip/hip_runtime.h>
#include <math.h>

// GptOssRouter: T=16384, H=2880, E=128, K=4.
// r26 = r21 restored verbatim (session best: 79.09us, passed).
// SINGLE-PASS FP16 fused kernel: fp16 RNE logit err sigma ~4.3e-4 ->
// certified-gap TAU=4e-3 (~6.6 sigma of diff-err): fast path = fp32 softmax
// of fp16-GEMM logits; ~5% of tokens flagged -> fp64 rescore of their top-8
// (order == float64 numpy reference).
// K0: w pre-convert fp32->fp16 (RNE) into d_ws as 16x16x32 B-frag tiles.
// K1: 32 tok x 128 exp per block, grid=512, depth-3 reg/LDS pipeline,
//     swizzled fp16 x-LDS (128B rows), w frags register-direct from d_ws.

#define T_TOK 16384
#define HDIM  2880
#define EEXP  128
#define KTOP  4

#define TM   32
#define NT   256
#define KC   64              // halfs per chunk per row
#define NCH  (HDIM / KC)     // 45 = 15 * 3
#define XBUF 4096            // 32 rows * 128 B fp16
#define TAU  4e-3f

typedef __attribute__((ext_vector_type(8))) _Float16 f16x8;
typedef __attribute__((ext_vector_type(4))) float    f32x4;

#define MFMA(a, b, c) __builtin_amdgcn_mfma_f32_16x16x32_f16((a), (b), (c), 0, 0, 0)

// ---------------- K0: w pre-convert into fragment-tiled fp16 ----------------
__global__ __launch_bounds__(256) void w_cvt(
    const float* __restrict__ w, char* __restrict__ wp)
{
    const int gid  = blockIdx.x * 256 + threadIdx.x;   // 46080 = 720 tiles * 64
    const int lane = gid & 63;
    const int q    = gid >> 6;        // 0..719
    const int ks   = q & 1;
    const int q2   = q >> 1;          // 0..359
    const int c    = q2 % NCH;
    const int F    = q2 / NCH;        // 0..7
    const int e    = F * 16 + (lane & 15);
    const int k0   = c * 64 + ks * 32 + (lane >> 4) * 8;

    const float* src = w + (size_t)e * HDIM + k0;
    float4 v0 = *(const float4*)(src);
    float4 v1 = *(const float4*)(src + 4);
    union { _Float16 h[8]; uint4 u; } H;
    H.h[0] = (_Float16)v0.x; H.h[1] = (_Float16)v0.y;
    H.h[2] = (_Float16)v0.z; H.h[3] = (_Float16)v0.w;
    H.h[4] = (_Float16)v1.x; H.h[5] = (_Float16)v1.y;
    H.h[6] = (_Float16)v1.z; H.h[7] = (_Float16)v1.w;
    const int tile = (F * NCH + c) * 2 + ks;
    *(uint4*)(wp + (size_t)tile * 1024 + lane * 16) = H.u;
}

// x staging: float4 -> 4 fp16 (RNE), 8B at swizzled slot within 128B row.
static __device__ __forceinline__ void cvt_write128(char* base, int off, float4 v) {
    union { _Float16 h[4]; uint2 u; } U;
    U.h[0] = (_Float16)v.x; U.h[1] = (_Float16)v.y;
    U.h[2] = (_Float16)v.z; U.h[3] = (_Float16)v.w;
    *(uint2*)(base + off) = U.u;
}

// ---------------- K1: fused GEMM + selection --------------------------------
__global__ __launch_bounds__(NT, 2) void router_fused(
    const float* __restrict__ x, const char* __restrict__ wp,
    const float* __restrict__ w, const float* __restrict__ bias,
    float* __restrict__ out)
{
    __shared__ char smem[20480];        // 3 x-bufs (12KB) / epilogue overlay
    const int tid  = threadIdx.x;
    const int tok0 = blockIdx.x * TM;
    const int lane = tid & 63;
    const int wv   = tid >> 6;          // expert 32-group 0..3
    const int r    = lane & 15;
    const int g    = lane >> 4;

    char* xb0 = smem;
    char* xb1 = smem + XBUF;
    char* xb2 = smem + 2 * XBUF;

    // x staging map: 512 float4 / 256 thr = 2 per thread
    int xoff[2];
    const float* xptr[2];
#pragma unroll
    for (int i = 0; i < 2; ++i) {
        int f = tid + i * NT;
        int row = f >> 4, c4 = f & 15;
        xoff[i] = row * 128 + ((((c4 >> 1) ^ (row & 7)) << 4) | ((c4 & 1) << 3));
        xptr[i] = x + (size_t)(tok0 + row) * HDIM + c4 * 4;
    }

    // a-frag read offsets: [tokfrag][ks]; logical slot = ks*4+g, XOR row&7
    int aoff[2][2];
#pragma unroll
    for (int tf = 0; tf < 2; ++tf) {
        int row = tf * 16 + r;
#pragma unroll
        for (int ks = 0; ks < 2; ++ks)
            aoff[tf][ks] = row * 128 + (((ks * 4 + g) ^ (row & 7)) << 4);
    }

    f32x4 a00 = {0.f, 0.f, 0.f, 0.f}, a01 = a00, a10 = a00, a11 = a00;

#define LOADX(pf, cc) do {                                            \
        pf[0] = *(const float4*)(xptr[0] + (cc) * KC);                \
        pf[1] = *(const float4*)(xptr[1] + (cc) * KC); } while (0)

#define WRITEX(pf, bb) do {                                           \
        cvt_write128((bb), xoff[0], pf[0]);                           \
        cvt_write128((bb), xoff[1], pf[1]); } while (0)

    // w frag tiles: W[F2*2 + ks]
#define LOADW(W, cc) do {                                             \
        _Pragma("unroll")                                             \
        for (int F2 = 0; F2 < 2; ++F2)                                \
        _Pragma("unroll")                                             \
        for (int ks_ = 0; ks_ < 2; ++ks_)                             \
            W[F2*2 + ks_] = *(const f16x8*)(wp +                      \
                (size_t)(((wv*2 + F2) * NCH + (cc)) * 2 + ks_) * 1024 \
                + lane * 16); } while (0)

#define MFMA_CHUNK(cb, W) do {                                        \
        _Pragma("unroll")                                             \
        for (int ks_ = 0; ks_ < 2; ++ks_) {                           \
            f16x8 a0 = *(const f16x8*)((cb) + aoff[0][ks_]);          \
            f16x8 a1 = *(const f16x8*)((cb) + aoff[1][ks_]);          \
            a00 = MFMA(a0, W[ks_],     a00);                          \
            a01 = MFMA(a0, W[2 + ks_], a01);                          \
            a10 = MFMA(a1, W[ks_],     a10);                          \
            a11 = MFMA(a1, W[2 + ks_], a11);                          \
        } } while (0)

    float4 pfA[2], pfB[2], pfC[2];
    f16x8 wA[4], wB[4], wC[4];

    // prologue: chunks 0..2 in regs, chunk 0 -> xb0; w chunks 0,1 in regs
    LOADX(pfA, 0); LOADX(pfB, 1); LOADX(pfC, 2);
    LOADW(wA, 0); LOADW(wB, 1);
    WRITEX(pfA, xb0);
    __syncthreads();

    for (int c = 0; c < NCH; c += 3) {
        // ---- phase 0: chunk c on xb0 / wA --------------------------------
        if (c + 3 < NCH) LOADX(pfA, c + 3);
        LOADW(wC, c + 2);
        MFMA_CHUNK(xb0, wA);
        WRITEX(pfB, xb1);                 // chunk c+1 (loaded 3 phases ago)
        __syncthreads();
        // ---- phase 1: chunk c+1 on xb1 / wB ------------------------------
        if (c + 3 < NCH) LOADW(wA, c + 3);
        if (c + 4 < NCH) LOADX(pfB, c + 4);
        MFMA_CHUNK(xb1, wB);
        WRITEX(pfC, xb2);                 // chunk c+2
        __syncthreads();
        // ---- phase 2: chunk c+2 on xb2 / wC ------------------------------
        if (c + 4 < NCH) LOADW(wB, c + 4);
        if (c + 5 < NCH) LOADX(pfC, c + 5);
        MFMA_CHUNK(xb2, wC);
        if (c + 3 < NCH) WRITEX(pfA, xb0); // chunk c+3
        __syncthreads();
    }

    // -------- logits(+bias) -> LDS [32][130] --------------------------------
    float* logitsL = (float*)smem;
    const float bv0 = bias[wv * 32 + r];
    const float bv1 = bias[wv * 32 + 16 + r];
#pragma unroll
    for (int q = 0; q < 4; ++q) {
        int m0 = g * 4 + q, m1 = m0 + 16;
        int e0 = wv * 32 + r, e1 = e0 + 16;
        logitsL[m0 * 130 + e0] = a00[q] + bv0;
        logitsL[m0 * 130 + e1] = a01[q] + bv1;
        logitsL[m1 * 130 + e0] = a10[q] + bv0;
        logitsL[m1 * 130 + e1] = a11[q] + bv1;
    }
    float*  cvf = (float*) (smem + 16640);   // [32][8]
    int*    cie = (int*)   (smem + 17664);   // [32][8]
    int*    flg = (int*)   (smem + 18688);   // [32]
    double* svd = (double*)(smem + 18816);   // [32][4]
    int*    sid = (int*)   (smem + 19840);   // [32][4]
    double* cvd = (double*)(smem + 20352);   // [8]
    __syncthreads();

    // -------- stripe top-8: thread (t, s) scans experts [s*16, s*16+16) -----
    {
        const int t = tid >> 3, s = tid & 7;
        float v[8]; int id[8];
#pragma unroll
        for (int k = 0; k < 8; ++k) { v[k] = -3.4e38f; id[k] = 0x7fffffff; }
        for (int jj = 0; jj < 16; ++jj) {
            float lv = logitsL[t * 130 + s * 16 + jj];
            int   e  = s * 16 + jj;
            bool gt[8];
#pragma unroll
            for (int k = 0; k < 8; ++k)
                gt[k] = (lv > v[k]) || (lv == v[k] && e < id[k]);
#pragma unroll
            for (int k = 7; k >= 1; --k)
                if (gt[k - 1]) { v[k] = v[k - 1]; id[k] = id[k - 1]; }
#pragma unroll
            for (int k = 0; k < 8; ++k) {
                bool put = gt[k] && (k == 0 || !gt[k - 1]);
                if (put) { v[k] = lv; id[k] = e; }
            }
        }
#pragma unroll
        for (int rd = 0; rd < 8; ++rd) {
            float hv = v[0]; int hi = id[0];
#pragma unroll
            for (int off = 1; off < 8; off <<= 1) {
                float ov = __shfl_xor(hv, off);
                int   oi = __shfl_xor(hi, off);
                if (ov > hv || (ov == hv && oi < hi)) { hv = ov; hi = oi; }
            }
            if (s == 0) { cvf[t * 8 + rd] = hv; cie[t * 8 + rd] = hi; }
            bool mine = (v[0] == hv) && (id[0] == hi);
            if (mine) {
#pragma unroll
                for (int k = 0; k < 7; ++k) { v[k] = v[k + 1]; id[k] = id[k + 1]; }
                v[7] = -3.4e38f; id[7] = 0x7fffffff;
            }
        }
    }
    __syncthreads();

    // -------- certified-gap test + fast-path fill ---------------------------
    if (tid < TM) {
        float gmin = 3.4e38f;
#pragma unroll
        for (int k = 0; k < 4; ++k)
            gmin = fminf(gmin, cvf[tid * 8 + k] - cvf[tid * 8 + k + 1]);
        flg[tid] = (gmin < TAU);
    }
    if (tid < 128) {
        int t2 = tid >> 2, k = tid & 3;
        svd[t2 * 4 + k] = (double)cvf[t2 * 8 + k];
        sid[t2 * 4 + k] = cie[t2 * 8 + k];
    }
    __syncthreads();

    // -------- slow path (~5% tokens): fp64 rescore, 2 candidates per wave ---
    for (int ts = 0; ts < TM; ++ts) {
        if (!flg[ts]) continue;              // uniform across block
#pragma unroll
        for (int h2 = 0; h2 < 2; ++h2) {
            const int cand = wv * 2 + h2;
            const int ce = cie[ts * 8 + cand];
            const float4* xr = (const float4*)(x + (size_t)(tok0 + ts) * HDIM);
            const float4* wr = (const float4*)(w + (size_t)ce * HDIM);
            double q0 = 0.0, q1 = 0.0, q2 = 0.0, q3 = 0.0;
            for (int i2 = 0; i2 < 12; ++i2) {
                int fi = lane + i2 * 64;
                if (fi < HDIM / 4) {
                    float4 xv = xr[fi];
                    float4 wv4 = wr[fi];
                    q0 = fma((double)xv.x, (double)wv4.x, q0);
                    q1 = fma((double)xv.y, (double)wv4.y, q1);
                    q2 = fma((double)xv.z, (double)wv4.z, q2);
                    q3 = fma((double)xv.w, (double)wv4.w, q3);
                }
            }
            double accd = (q0 + q2) + (q1 + q3);
#pragma unroll
            for (int off = 32; off > 0; off >>= 1)
                accd += __shfl_xor(accd, off);
            if (lane == 0) cvd[cand] = accd + (double)bias[ce];
        }
        __syncthreads();
        if (tid < 8) {                        // fp64 rank among 8 candidates
            double mv = cvd[tid]; int mi2 = cie[ts * 8 + tid];
            int rk = 0;
#pragma unroll
            for (int j2 = 0; j2 < 8; ++j2) {
                double oj = cvd[j2];
                rk += (oj > mv) || (oj == mv && cie[ts * 8 + j2] < mi2);
            }
            if (rk < 4) { svd[ts * 4 + rk] = mv; sid[ts * 4 + rk] = mi2; }
        }
        __syncthreads();
    }

    // -------- softmax + outputs ---------------------------------------------
    float* srow = (float*)smem;              // [32][128], overlays dead logits
    float4 z4 = make_float4(0.f, 0.f, 0.f, 0.f);
#pragma unroll
    for (int i = 0; i < 4; ++i)
        ((float4*)srow)[tid + i * NT] = z4;
    __syncthreads();

    if (tid < TM) {
        double m  = svd[tid * 4];
        double e0 = exp(svd[tid * 4 + 0] - m), e1 = exp(svd[tid * 4 + 1] - m);
        double e2 = exp(svd[tid * 4 + 2] - m), e3 = exp(svd[tid * 4 + 3] - m);
        double inv = 1.0 / ((e0 + e1) + (e2 + e3));
        float* oidx = out + (size_t)T_TOK * EEXP + (size_t)(tok0 + tid) * KTOP;
        int i0 = sid[tid * 4 + 0], i1 = sid[tid * 4 + 1];
        int i2 = sid[tid * 4 + 2], i3 = sid[tid * 4 + 3];
        oidx[0] = (float)i0; oidx[1] = (float)i1;
        oidx[2] = (float)i2; oidx[3] = (float)i3;
        srow[tid * EEXP + i0] = (float)(e0 * inv);
        srow[tid * EEXP + i1] = (float)(e1 * inv);
        srow[tid * EEXP + i2] = (float)(e2 * inv);
        srow[tid * EEXP + i3] = (float)(e3 * inv);
    }
    __syncthreads();

    float4* orow = (float4*)(out + (size_t)tok0 * EEXP);
#pragma unroll
    for (int i = 0; i < 4; ++i)
        orow[tid + i * NT] = ((float4*)srow)[tid + i * NT];
}

extern "C" void kernel_launch(void* const* d_in, const int* in_sizes, int n_in,
                              void* d_out, int out_size, void* d_ws, size_t ws_size,
                              hipStream_t stream) {
    const float* x    = (const float*)d_in[0];
    const float* w    = (const float*)d_in[1];
    const float* bias = (const float*)d_in[2];
    float* out        = (float*)d_out;
    char*  wp         = (char*)d_ws;   // 720 KiB (8*45*2 tiles * 1KB)

    hipLaunchKernelGGL(w_cvt, dim3(180), dim3(256), 0, stream, w, wp);
    hipLaunchKernelGGL(router_fused, dim3(T_TOK / TM), dim3(NT), 0, stream,
                       x, wp, w, bias, out);
}